// Round 3
// baseline (375.104 us; speedup 1.0000x reference)
//
#include <hip/hip_runtime.h>

// Problem constants (fixed by the reference): B=8, S=512, D=384, VOCAB=50257.
#define BB 8
#define SS 512
#define DD 384
#define D4 (DD / 4)           // 96 float4 per row
#define K2 (DD * DD)          // 147456 = flattened (d,e)
#define LCH 16                // list entries per pass (LDS-resident); observed total<=16
#define OT 4                  // o-rows per block: each LDS read-set feeds 4 Wc rows
#define KCH 8                 // k-chunks (grid.y); u holds KCH partials, plain stores
#define NT 256                // 4 waves/block; 3 blocks/CU (LDS ~52K) -> 12 waves/CU
#define GROUPS (K2 / 4)       // 36864 float4-groups over k
#define GPC (GROUPS / KCH)    // 4608 groups per chunk
#define ITERS (GPC / NT)      // 18
#define MAXL_CAP 1024
#define SEG_CAP 256           // per-wave list segment cap (4 waves -> 1024 total)

// ws layout (bytes): [0,16) count | [16, 16+4*MAXL_CAP) list | u partials
#define WS_LIST_OFF 16
#define WS_U_OFF (WS_LIST_OFF + 4 * MAXL_CAP)   // 4112, 16B-aligned

// ---------------------------------------------------------------------------
// Recursive-halving cross-lane reduce: after all steps, lane L of the wave
// holds the 64-lane total of value index L. 63 shuffles total.
template <int HALF>
__device__ __forceinline__ void fold_step(float* red, int lane) {
#pragma unroll
    for (int i = 0; i < HALF; ++i) {
        float lo = red[i], hi = red[i + HALF];
        float send = (lane & HALF) ? lo : hi;
        float recv = __shfl_xor(send, HALF, 64);
        red[i] = (lane & HALF) ? (hi + recv) : (lo + recv);
    }
}

// ---------------------------------------------------------------------------
// Kernel 1: u[c,l,o] = partial_k p[l,k]*Wc[o,k] over k-chunk c, where
// k = d*384+e, p[l,k] = tok[l,d]*tanh(tok[l,e]).
// Self-contained: every block deterministically rebuilds the qualifying-s2
// list via per-wave ballot compaction (position-sorted, identical across
// blocks; no atomics -> no cross-block order divergence), gathers+tanh's the
// tok rows into LDS, then streams Wc once (226.5 MB -> ~36 us HBM floor).
// Block (0,0) publishes list+count to ws for finalize.
__global__ __launch_bounds__(NT, 3) void bilinear_kernel(
    const float* __restrict__ Wc, const float* __restrict__ tok_table,
    const int* __restrict__ tokens, const int* __restrict__ heads,
    int* __restrict__ countp, int* __restrict__ list_ws,
    float* __restrict__ u, int maxl) {
    __shared__ alignas(16) float tokS[LCH][DD];   // also scratch for list segs
    __shared__ alignas(16) float depS[LCH][DD];
    __shared__ int lstS[MAXL_CAP];                // 4 KB, persists whole kernel
    __shared__ int cw[4];

    const int tid = threadIdx.x;
    const int lane = tid & 63;
    const int wid = tid >> 6;
    const int o0 = blockIdx.x * OT;          // 96 o-quads
    const int g0 = blockIdx.y * GPC;         // k-chunk base (float4 groups)

    // ---- in-block deterministic list build (4 waves, 16 chunks of 64 each)
    {
        int* lstSeg = (int*)&tokS[0][0];     // [4][SEG_CAP] scratch overlay
        int cnt = 0;
#pragma unroll 4
        for (int cc = 0; cc < 16; ++cc) {
            int pos = (wid * 16 + cc) * 64 + lane;
            int h = heads[pos];
            bool pred = (heads[(pos & ~(SS - 1)) + h] == 0);
            unsigned long long m = __ballot(pred);
            if (pred) {
                int idx = cnt + __popcll(m & ((1ull << lane) - 1ull));
                if (idx < SEG_CAP) lstSeg[wid * SEG_CAP + idx] = pos;
            }
            cnt += (int)__popcll(m);
        }
        if (lane == 0) cw[wid] = cnt > SEG_CAP ? SEG_CAP : cnt;
        __syncthreads();
        int offW[4];
        offW[0] = 0;
#pragma unroll
        for (int w = 1; w < 4; ++w) offW[w] = offW[w - 1] + cw[w - 1];
        // compact segments into the persistent flat list (position-sorted)
        for (int i = lane; i < cw[wid]; i += 64) {
            int dst = offW[wid] + i;
            if (dst < MAXL_CAP) lstS[dst] = lstSeg[wid * SEG_CAP + i];
        }
        __syncthreads();                     // lstSeg (tokS) dead after this
    }
    int total = cw[0] + cw[1] + cw[2] + cw[3];
    if (total > maxl) total = maxl;

    // ---- publish list/count for finalize (one block only)
    if (blockIdx.x == 0 && blockIdx.y == 0) {
        if (tid == 0) *countp = total;
        for (int i = tid; i < total; i += NT) list_ws[i] = lstS[i];
    }

    for (int cb = 0; cb < total; cb += LCH) {
        // ---- stage tok/dep rows into LDS (gather + tanh, zero-pad dead rows)
        for (int idx = tid; idx < LCH * DD; idx += NT) {
            int l = idx / DD;
            int i = idx - l * DD;
            float t = 0.f;
            if (cb + l < total)
                t = tok_table[(size_t)tokens[lstS[cb + l]] * DD + i];
            tokS[l][i] = t;
            depS[l][i] = tanhf(t);           // t==0 -> dep==0 -> contributes 0
        }
        __syncthreads();

        const int lmax = total - cb;         // live entries this pass (wave-uniform)

        float acc[LCH][OT];
#pragma unroll
        for (int l = 0; l < LCH; ++l)
#pragma unroll
            for (int j = 0; j < OT; ++j) acc[l][j] = 0.f;

        // ---- prefetch iteration 0 (4 o-rows)
        const float* wbase = Wc + (size_t)o0 * K2;
        float4 wv[OT], nv[OT];
        {
            const float* wp = wbase + 4 * (size_t)(g0 + tid);
#pragma unroll
            for (int r = 0; r < OT; ++r) wv[r] = *(const float4*)(wp + (size_t)r * K2);
        }

#pragma unroll 1
        for (int it = 0; it < ITERS; ++it) {
            int gc = g0 + it * NT + tid;

            // prefetch next iteration; clamp addr on last iter (loads stay valid,
            // values unused) to avoid a branch + zero-init
            {
                int gn = (it + 1 < ITERS) ? (gc + NT) : (g0 + tid);
                const float* wp = wbase + 4 * (size_t)gn;
#pragma unroll
                for (int r = 0; r < OT; ++r) nv[r] = *(const float4*)(wp + (size_t)r * K2);
            }

            int d = gc / 96;                  // near-uniform across wave (<=3 values)
            int e4 = gc - d * 96;             // float4 index within dep row

#pragma unroll
            for (int l4 = 0; l4 < LCH / 4; ++l4) {
                if (l4 * 4 < lmax) {          // wave-uniform skip of dead 4-groups
#pragma unroll
                    for (int li = 0; li < 4; ++li) {
                        const int l = l4 * 4 + li;
                        float td = tokS[l][d];
                        float4 dv = *(const float4*)(&depS[l][e4 * 4]);
                        float px = td * dv.x, py = td * dv.y;
                        float pz = td * dv.z, pw = td * dv.w;
#pragma unroll
                        for (int r = 0; r < OT; ++r)
                            acc[l][r] += px * wv[r].x + py * wv[r].y +
                                         pz * wv[r].z + pw * wv[r].w;
                    }
                }
            }
#pragma unroll
            for (int r = 0; r < OT; ++r) wv[r] = nv[r];
        }

        // ---- fold-reduce all 64 (l,j) values across the wave (63 shuffles)
        float red[LCH * OT];
#pragma unroll
        for (int k = 0; k < LCH * OT; ++k) red[k] = acc[k >> 2][k & 3];
        fold_step<32>(red, lane);
        fold_step<16>(red, lane);
        fold_step<8>(red, lane);
        fold_step<4>(red, lane);
        fold_step<2>(red, lane);
        fold_step<1>(red, lane);
        // lane L now holds wave total for l=L>>2, j=L&3

        __syncthreads();                     // done reading tokS/depS
        float* redS = &tokS[0][0];           // reuse staging LDS: 4 waves x 64
        redS[wid * 64 + lane] = red[0];
        __syncthreads();
        if (tid < 64) {
            int l = tid >> 2, j = tid & 3;
            if (l < lmax && l < LCH) {
                float s = redS[tid] + redS[64 + tid] + redS[128 + tid] + redS[192 + tid];
                // plain store: (chunk, list-row, o) partial
                u[((size_t)blockIdx.y * maxl + (cb + l)) * DD + o0 + j] = s;
            }
        }
        __syncthreads();  // protect LDS before next chunk's staging
    }
}

// ---------------------------------------------------------------------------
// Kernel 2: full output. Grid = B*S blocks x 128. Dead rows (heads!=0) write
// float4 zeros (replaces the hipMemsetAsync dispatch); the ~1 live row per
// batch computes base + scatter contributions, summing KCH u-partials.
__global__ __launch_bounds__(128) void finalize_kernel(
    const int* __restrict__ heads, const float* __restrict__ Wr,
    const float* __restrict__ bc, const float* __restrict__ br,
    const int* __restrict__ list, const int* __restrict__ countp,
    const float* __restrict__ u, float* __restrict__ out, int maxl) {
    int row = blockIdx.x;
    int tid = threadIdx.x;

    if (heads[row] != 0) {
        if (tid < D4)
            ((float4*)(out + (size_t)row * DD))[tid] = make_float4(0.f, 0.f, 0.f, 0.f);
        return;
    }
    int b = row >> 9;     // /512
    int s1 = row & 511;

    // parallel sumw over Wr[0..511]: 128 threads x 4, wave reduce, LDS combine
    __shared__ float wsum[2];
    float w = Wr[tid] + Wr[tid + 128] + Wr[tid + 256] + Wr[tid + 384];
#pragma unroll
    for (int off = 32; off > 0; off >>= 1) w += __shfl_down(w, off, 64);
    if ((tid & 63) == 0) wsum[tid >> 6] = w;
    __syncthreads();
    float sumw = wsum[0] + wsum[1];
    float brv = br[0];

    int total = *countp;
    if (total > maxl) total = maxl;

    for (int o = tid; o < DD; o += 128) {
        float bco = bc[o];
        float t_off = tanhf(bco);
        float val = t_off * sumw + brv;
        for (int l = 0; l < total; ++l) {
            int pos = list[l];
            if ((pos >> 9) == b && heads[pos] == s1) {
                float sum = 0.f;
#pragma unroll
                for (int c = 0; c < KCH; ++c)
                    sum += u[((size_t)c * maxl + l) * DD + o];
                val += (tanhf(sum + bco) - t_off) * Wr[pos & 511];
            }
        }
        out[(size_t)row * DD + o] = val;
    }
}

// ---------------------------------------------------------------------------
extern "C" void kernel_launch(void* const* d_in, const int* in_sizes, int n_in,
                              void* d_out, int out_size, void* d_ws, size_t ws_size,
                              hipStream_t stream) {
    const int* tokens = (const int*)d_in[0];
    // d_in[1] = dep_types: computed-but-discarded in the reference (bug preserved)
    const int* heads = (const int*)d_in[2];
    const float* tok_table = (const float*)d_in[3];
    const float* Wc = (const float*)d_in[4];
    const float* bc = (const float*)d_in[5];
    const float* Wr = (const float*)d_in[6];
    const float* br = (const float*)d_in[7];
    float* out = (float*)d_out;

    char* ws = (char*)d_ws;
    int* countp = (int*)ws;
    int* list = (int*)(ws + WS_LIST_OFF);

    long avail = (long)ws_size - WS_U_OFF;
    long per_row = (long)KCH * DD * 4;         // 12288 (u partials only)
    long maxl_l = avail / per_row;
    int maxl = maxl_l < 0 ? 0 : (maxl_l > MAXL_CAP ? MAXL_CAP : (int)maxl_l);

    float* u = (float*)(ws + WS_U_OFF);

    // Two dispatches total. No memsets: bilinear writes count/list/u before
    // any read; finalize writes every output row (zeros or values).
    bilinear_kernel<<<dim3(DD / OT, KCH), NT, 0, stream>>>(
        Wc, tok_table, tokens, heads, countp, list, u, maxl);
    finalize_kernel<<<BB * SS, 128, 0, stream>>>(
        heads, Wr, bc, br, list, countp, u, out, maxl);
}